// Round 1
// baseline (50.042 us; speedup 1.0000x reference)
//
#include <hip/hip_runtime.h>

#define HW_BIG   1e10f
#define LOSS_EPS 1e-8f

// ---------------------------------------------------------------------------
// Kernel 1: masks -> 4-neighbor boundary flags (image border = background).
// b[img][x][y] = mask && !(up && down && left && right)
// ---------------------------------------------------------------------------
__global__ void k_boundary(const float* __restrict__ inp,
                           const float* __restrict__ tgt,
                           unsigned char* __restrict__ b_ib,
                           unsigned char* __restrict__ b_lb) {
    const int img = blockIdx.x >> 8;
    const int x   = blockIdx.x & 255;
    const int y   = threadIdx.x;
    const float* ip = inp + (size_t)img * 65536;
    const float* tp = tgt + (size_t)img * 65536;
    const int idx = x * 256 + y;

    // predicted mask: sigmoid(v) > 0.5  <=>  v > 0
    bool mc = ip[idx] > 0.0f;
    bool mu = (x > 0)   ? (ip[idx - 256] > 0.0f) : false;
    bool md = (x < 255) ? (ip[idx + 256] > 0.0f) : false;
    bool ml = (y > 0)   ? (ip[idx - 1]   > 0.0f) : false;
    bool mr = (y < 255) ? (ip[idx + 1]   > 0.0f) : false;
    b_ib[(size_t)img * 65536 + idx] = (mc && !(mu && md && ml && mr)) ? 1 : 0;

    bool tc = tp[idx] > 0.5f;
    bool tu = (x > 0)   ? (tp[idx - 256] > 0.5f) : false;
    bool td = (x < 255) ? (tp[idx + 256] > 0.5f) : false;
    bool tl = (y > 0)   ? (tp[idx - 1]   > 0.5f) : false;
    bool tr = (y < 255) ? (tp[idx + 1]   > 0.5f) : false;
    b_lb[(size_t)img * 65536 + idx] = (tc && !(tu && td && tl && tr)) ? 1 : 0;
}

// ---------------------------------------------------------------------------
// Kernel 2 (pass A): per column y, g[x][y] = min_{x'} (x-x')^2 + (b[x'][y]?0:BIG)
// Output u16 in [img][y][x] layout. 0xFFFF encodes "exactly BIG" (empty column);
// otherwise the exact integer squared distance (<= 65025).
// ---------------------------------------------------------------------------
__global__ void k_passA(const unsigned char* __restrict__ b_ib,
                        const unsigned char* __restrict__ b_lb,
                        unsigned short* __restrict__ gA_ib,
                        unsigned short* __restrict__ gA_lb) {
    __shared__ float c1[256];
    __shared__ float c2[256];
    const int img = blockIdx.x >> 8;
    const int y   = blockIdx.x & 255;
    const int x   = threadIdx.x;

    const unsigned char* p1 = b_ib + (size_t)img * 65536;
    const unsigned char* p2 = b_lb + (size_t)img * 65536;
    c1[x] = p1[x * 256 + y] ? 0.0f : HW_BIG;
    c2[x] = p2[x * 256 + y] ? 0.0f : HW_BIG;
    __syncthreads();

    float m1 = INFINITY, m2 = INFINITY;
    const float fx = (float)x;
#pragma unroll 8
    for (int xp = 0; xp < 256; ++xp) {
        float d = fx - (float)xp;            // d*d is an exact integer in f32
        m1 = fminf(m1, fmaf(d, d, c1[xp]));
        m2 = fminf(m2, fmaf(d, d, c2[xp]));
    }
    const size_t o = (size_t)blockIdx.x * 256 + x;   // [img][y][x]
    gA_ib[o] = (m1 >= 1e9f) ? (unsigned short)65535 : (unsigned short)m1;
    gA_lb[o] = (m2 >= 1e9f) ? (unsigned short)65535 : (unsigned short)m2;
}

// ---------------------------------------------------------------------------
// Kernel 3 (pass B + fused loss): per row x,
//   d2[x][y] = min_{y'} g[x][y'] + (y-y')^2   for both masks,
// then weight map + focal BCE, block tree-reduction -> partials[block].
// ---------------------------------------------------------------------------
__global__ void k_passB_loss(const unsigned short* __restrict__ gA_ib,
                             const unsigned short* __restrict__ gA_lb,
                             const unsigned char* __restrict__ b_ib,
                             const unsigned char* __restrict__ b_lb,
                             const float* __restrict__ inp,
                             const float* __restrict__ tgt,
                             float* __restrict__ partials) {
    __shared__ float g1[256];
    __shared__ float g2[256];
    __shared__ float wsum[4];
    const int img = blockIdx.x >> 8;
    const int x   = blockIdx.x & 255;
    const int y   = threadIdx.x;

    // load column x of gA (gA layout [img][y'][x]); thread y loads y'=y
    {
        const size_t o = (size_t)img * 65536 + (size_t)y * 256 + x;
        unsigned short u1 = gA_ib[o];
        unsigned short u2 = gA_lb[o];
        g1[y] = (u1 == 65535) ? HW_BIG : (float)u1;
        g2[y] = (u2 == 65535) ? HW_BIG : (float)u2;
    }
    __syncthreads();

    float m1 = INFINITY, m2 = INFINITY;
    const float fy = (float)y;
#pragma unroll 8
    for (int yp = 0; yp < 256; ++yp) {
        float d = fy - (float)yp;
        m1 = fminf(m1, fmaf(d, d, g1[yp]));   // d2 to image boundary
        m2 = fminf(m2, fmaf(d, d, g2[yp]));   // d2 to label boundary
    }

    const size_t idx = (size_t)img * 65536 + (size_t)x * 256 + y;
    const float v = inp[idx];
    const float t = tgt[idx];
    const float p = 1.0f / (1.0f + expf(-v));
    const bool fib = b_ib[idx] != 0;
    const bool flb = b_lb[idx] != 0;

    float w = 1.0f;
    if (flb) w += expf(-sqrtf(m1));   // THETA=1, SIGMA=1
    if (fib) w += expf(-sqrtf(m2));

    // GAMMA = 1
    float loss = w * (-(1.0f - p) * t * logf(p + LOSS_EPS)
                      - p * (1.0f - t) * logf(1.0f - p + LOSS_EPS));

    // deterministic block reduction: wave shfl tree + 4 wave partials
    float s = loss;
#pragma unroll
    for (int off = 32; off > 0; off >>= 1) s += __shfl_down(s, off, 64);
    const int lane = y & 63, wv = y >> 6;
    if (lane == 0) wsum[wv] = s;
    __syncthreads();
    if (y == 0) partials[blockIdx.x] = (wsum[0] + wsum[1]) + (wsum[2] + wsum[3]);
}

// ---------------------------------------------------------------------------
// Kernel 4: reduce partials -> mean (single block, fixed order, double accum)
// ---------------------------------------------------------------------------
__global__ void k_reduce(const float* __restrict__ partials, int n,
                         float* __restrict__ out, double inv_count) {
    __shared__ double sw[4];
    const int tid = threadIdx.x;
    double s = 0.0;
    for (int i = tid; i < n; i += 256) s += (double)partials[i];
#pragma unroll
    for (int off = 32; off > 0; off >>= 1) s += __shfl_down(s, off, 64);
    const int lane = tid & 63, wv = tid >> 6;
    if (lane == 0) sw[wv] = s;
    __syncthreads();
    if (tid == 0) out[0] = (float)(((sw[0] + sw[1]) + (sw[2] + sw[3])) * inv_count);
}

// ---------------------------------------------------------------------------
extern "C" void kernel_launch(void* const* d_in, const int* in_sizes, int n_in,
                              void* d_out, int out_size, void* d_ws, size_t ws_size,
                              hipStream_t stream) {
    const float* inp = (const float*)d_in[0];
    const float* tgt = (const float*)d_in[1];
    float* out = (float*)d_out;

    const int total = in_sizes[0];          // B*256*256
    const int nimg  = total / 65536;        // B = 8
    const int nblk  = nimg * 256;           // 2048

    char* ws = (char*)d_ws;
    unsigned char*  b_ib  = (unsigned char*)ws;
    unsigned char*  b_lb  = b_ib + (size_t)nimg * 65536;
    unsigned short* gA_ib = (unsigned short*)(b_lb + (size_t)nimg * 65536);
    unsigned short* gA_lb = gA_ib + (size_t)nimg * 65536;
    float*          parts = (float*)(gA_lb + (size_t)nimg * 65536);

    k_boundary  <<<nblk, 256, 0, stream>>>(inp, tgt, b_ib, b_lb);
    k_passA     <<<nblk, 256, 0, stream>>>(b_ib, b_lb, gA_ib, gA_lb);
    k_passB_loss<<<nblk, 256, 0, stream>>>(gA_ib, gA_lb, b_ib, b_lb, inp, tgt, parts);
    k_reduce    <<<1,    256, 0, stream>>>(parts, nblk, out, 1.0 / (double)total);
}

// Round 2
// 26.748 us; speedup vs baseline: 1.8708x; 1.8708x over previous
//
#include <hip/hip_runtime.h>

#define HW_BIG   1e10f
#define LOSS_EPS 1e-8f

// ---------------------------------------------------------------------------
// Kernel 1: masks -> 4-neighbor boundary flags packed as row bitmasks.
// rows_*[img][x][w] (w=0..3) bit b = boundary flag at (x, y=w*64+b).
// ---------------------------------------------------------------------------
__global__ void k_boundary_bits(const float* __restrict__ inp,
                                const float* __restrict__ tgt,
                                unsigned long long* __restrict__ rows_ib,
                                unsigned long long* __restrict__ rows_lb) {
    const int img = blockIdx.x >> 8;
    const int x   = blockIdx.x & 255;
    const int y   = threadIdx.x;
    const float* ip = inp + (size_t)img * 65536;
    const float* tp = tgt + (size_t)img * 65536;
    const int idx = x * 256 + y;

    // predicted mask: sigmoid(v) > 0.5  <=>  v > 0
    bool mc = ip[idx] > 0.0f;
    bool mu = (x > 0)   ? (ip[idx - 256] > 0.0f) : false;
    bool md = (x < 255) ? (ip[idx + 256] > 0.0f) : false;
    bool ml = (y > 0)   ? (ip[idx - 1]   > 0.0f) : false;
    bool mr = (y < 255) ? (ip[idx + 1]   > 0.0f) : false;
    bool fib = mc && !(mu && md && ml && mr);

    bool tc = tp[idx] > 0.5f;
    bool tu = (x > 0)   ? (tp[idx - 256] > 0.5f) : false;
    bool td = (x < 255) ? (tp[idx + 256] > 0.5f) : false;
    bool tl = (y > 0)   ? (tp[idx - 1]   > 0.5f) : false;
    bool tr = (y < 255) ? (tp[idx + 1]   > 0.5f) : false;
    bool flb = tc && !(tu && td && tl && tr);

    unsigned long long b1 = __ballot(fib);   // 64-bit wave ballot, lane = y&63
    unsigned long long b2 = __ballot(flb);
    if ((y & 63) == 0) {
        const size_t ro = (size_t)blockIdx.x * 4 + (y >> 6);  // [img][x][w]
        rows_ib[ro] = b1;
        rows_lb[ro] = b2;
    }
}

// ---------------------------------------------------------------------------
// nearest set bit squared-distance in a 256-bit column mask (4 u64 words).
// returns -1 if the mask is empty, else exact (x - x')^2 <= 65025.
// ---------------------------------------------------------------------------
__device__ __forceinline__ int nearest_dist2(const unsigned long long* cm, int x) {
    const int xw = x >> 6, xb = x & 63;
    int best = 1 << 30;
    // nearest set bit at position <= x
    unsigned long long w = cm[xw] & (~0ULL >> (63 - xb));
    int j = xw;
    while (w == 0 && j > 0) w = cm[--j];
    if (w) { int hs = 63 - __builtin_clzll(w); best = x - (j * 64 + hs); }
    // nearest set bit at position >= x
    unsigned long long w2 = cm[xw] & (~0ULL << xb);
    int j2 = xw;
    while (w2 == 0 && j2 < 3) w2 = cm[++j2];
    if (w2) { int ls = __builtin_ctzll(w2); int du = (j2 * 64 + ls) - x; best = min(best, du); }
    if (best > 255) return -1;
    return best * best;
}

// ---------------------------------------------------------------------------
// Kernel 2 (pass A): per column y, g[x] = (nearest boundary row distance)^2,
// or 0xFFFF (=BIG) if the column has no boundary pixel. Output [img][y][x].
// Column mask built from row bitmasks via a ballot transpose.
// ---------------------------------------------------------------------------
__global__ void k_passA_bits(const unsigned long long* __restrict__ rows_ib,
                             const unsigned long long* __restrict__ rows_lb,
                             unsigned short* __restrict__ gA_ib,
                             unsigned short* __restrict__ gA_lb) {
    __shared__ unsigned long long cm1[4];
    __shared__ unsigned long long cm2[4];
    const int img = blockIdx.x >> 8;
    const int y   = blockIdx.x & 255;
    const int x   = threadIdx.x;
    const int yw = y >> 6, yb = y & 63;

    const size_t rbase = (size_t)img * 1024 + (size_t)x * 4 + yw;
    bool bit1 = (rows_ib[rbase] >> yb) & 1;
    bool bit2 = (rows_lb[rbase] >> yb) & 1;
    unsigned long long m1 = __ballot(bit1);  // bits over x within this wave
    unsigned long long m2 = __ballot(bit2);
    if ((x & 63) == 0) { cm1[x >> 6] = m1; cm2[x >> 6] = m2; }
    __syncthreads();

    int d1 = nearest_dist2(cm1, x);
    int d2 = nearest_dist2(cm2, x);
    const size_t o = (size_t)blockIdx.x * 256 + x;   // [img][y][x]
    gA_ib[o] = (d1 < 0) ? (unsigned short)65535 : (unsigned short)d1;
    gA_lb[o] = (d2 < 0) ? (unsigned short)65535 : (unsigned short)d2;
}

// ---------------------------------------------------------------------------
// Kernel 3 (pass B + fused loss): per row x,
//   d2[y] = min_{y'} g[y'] + (y-y')^2  via exact early-exit outward scan,
// then weight map + focal BCE, deterministic block reduction -> partials.
// ---------------------------------------------------------------------------
__global__ void k_passB_loss(const unsigned short* __restrict__ gA_ib,
                             const unsigned short* __restrict__ gA_lb,
                             const unsigned long long* __restrict__ rows_ib,
                             const unsigned long long* __restrict__ rows_lb,
                             const float* __restrict__ inp,
                             const float* __restrict__ tgt,
                             float* __restrict__ partials) {
    __shared__ float g1[256];
    __shared__ float g2[256];
    __shared__ float wsum[4];
    const int img = blockIdx.x >> 8;
    const int x   = blockIdx.x & 255;
    const int y   = threadIdx.x;

    // load column x of gA (layout [img][y'][x]); thread y loads y'=y
    {
        const size_t o = ((size_t)img * 256 + y) * 256 + x;
        unsigned short u1 = gA_ib[o];
        unsigned short u2 = gA_lb[o];
        g1[y] = (u1 == 65535) ? HW_BIG : (float)u1;
        g2[y] = (u2 == 65535) ? HW_BIG : (float)u2;
    }
    __syncthreads();

    // exact early-exit outward scan: once d^2 >= m for both, no candidate
    // g[y'] + d'^2 (g>=0, d' > d) can lower the min.
    float m1 = g1[y];
    float m2 = g2[y];
    for (int d = 1; d < 256; ++d) {
        const float fd2 = (float)(d * d);          // exact integer in f32
        if (fd2 >= m1 && fd2 >= m2) break;
        const int yl = y - d;
        if (yl >= 0)  { m1 = fminf(m1, g1[yl] + fd2); m2 = fminf(m2, g2[yl] + fd2); }
        const int yr = y + d;
        if (yr < 256) { m1 = fminf(m1, g1[yr] + fd2); m2 = fminf(m2, g2[yr] + fd2); }
    }

    const size_t rbase = (size_t)img * 1024 + (size_t)x * 4 + (y >> 6);
    const bool fib = (rows_ib[rbase] >> (y & 63)) & 1;
    const bool flb = (rows_lb[rbase] >> (y & 63)) & 1;

    const size_t idx = (size_t)img * 65536 + (size_t)x * 256 + y;
    const float v = inp[idx];
    const float t = tgt[idx];
    const float p = 1.0f / (1.0f + expf(-v));

    float w = 1.0f;
    if (flb) w += expf(-sqrtf(m1));   // THETA=1, SIGMA=1
    if (fib) w += expf(-sqrtf(m2));

    // GAMMA = 1
    float loss = w * (-(1.0f - p) * t * logf(p + LOSS_EPS)
                      - p * (1.0f - t) * logf(1.0f - p + LOSS_EPS));

    // deterministic block reduction: wave shfl tree + 4 wave partials
    float s = loss;
#pragma unroll
    for (int off = 32; off > 0; off >>= 1) s += __shfl_down(s, off, 64);
    const int lane = y & 63, wv = y >> 6;
    if (lane == 0) wsum[wv] = s;
    __syncthreads();
    if (y == 0) partials[blockIdx.x] = (wsum[0] + wsum[1]) + (wsum[2] + wsum[3]);
}

// ---------------------------------------------------------------------------
// Kernel 4: reduce partials -> mean (single block, fixed order, double accum)
// ---------------------------------------------------------------------------
__global__ void k_reduce(const float* __restrict__ partials, int n,
                         float* __restrict__ out, double inv_count) {
    __shared__ double sw[4];
    const int tid = threadIdx.x;
    double s = 0.0;
    for (int i = tid; i < n; i += 256) s += (double)partials[i];
#pragma unroll
    for (int off = 32; off > 0; off >>= 1) s += __shfl_down(s, off, 64);
    const int lane = tid & 63, wv = tid >> 6;
    if (lane == 0) sw[wv] = s;
    __syncthreads();
    if (tid == 0) out[0] = (float)(((sw[0] + sw[1]) + (sw[2] + sw[3])) * inv_count);
}

// ---------------------------------------------------------------------------
extern "C" void kernel_launch(void* const* d_in, const int* in_sizes, int n_in,
                              void* d_out, int out_size, void* d_ws, size_t ws_size,
                              hipStream_t stream) {
    const float* inp = (const float*)d_in[0];
    const float* tgt = (const float*)d_in[1];
    float* out = (float*)d_out;

    const int total = in_sizes[0];          // B*256*256
    const int nimg  = total / 65536;        // B = 8
    const int nblk  = nimg * 256;           // 2048

    char* ws = (char*)d_ws;
    unsigned long long* rows_ib = (unsigned long long*)ws;                       // nimg*256*4 u64
    unsigned long long* rows_lb = rows_ib + (size_t)nimg * 1024;
    unsigned short*     gA_ib   = (unsigned short*)(rows_lb + (size_t)nimg * 1024);
    unsigned short*     gA_lb   = gA_ib + (size_t)nimg * 65536;
    float*              parts   = (float*)(gA_lb + (size_t)nimg * 65536);

    k_boundary_bits<<<nblk, 256, 0, stream>>>(inp, tgt, rows_ib, rows_lb);
    k_passA_bits   <<<nblk, 256, 0, stream>>>(rows_ib, rows_lb, gA_ib, gA_lb);
    k_passB_loss   <<<nblk, 256, 0, stream>>>(gA_ib, gA_lb, rows_ib, rows_lb, inp, tgt, parts);
    k_reduce       <<<1,    256, 0, stream>>>(parts, nblk, out, 1.0 / (double)total);
}

// Round 3
// 25.619 us; speedup vs baseline: 1.9533x; 1.0441x over previous
//
#include <hip/hip_runtime.h>

#define HW_BIG   1e10f
#define LOSS_EPS 1e-8f

// ---------------------------------------------------------------------------
// nearest set bit squared-distance in a 256-bit mask (4 u64 words).
// returns -1 if the mask is empty, else exact (pos - pos')^2 <= 65025.
// ---------------------------------------------------------------------------
__device__ __forceinline__ int nearest_dist2(const unsigned long long* cm, int x) {
    const int xw = x >> 6, xb = x & 63;
    int best = 1 << 30;
    // nearest set bit at position <= x
    unsigned long long w = cm[xw] & (~0ULL >> (63 - xb));
    int j = xw;
    while (w == 0 && j > 0) w = cm[--j];
    if (w) { int hs = 63 - __builtin_clzll(w); best = x - (j * 64 + hs); }
    // nearest set bit at position >= x
    unsigned long long w2 = cm[xw] & (~0ULL << xb);
    int j2 = xw;
    while (w2 == 0 && j2 < 3) w2 = cm[++j2];
    if (w2) { int ls = __builtin_ctzll(w2); int du = (j2 * 64 + ls) - x; best = min(best, du); }
    if (best > 255) return -1;
    return best * best;
}

// ---------------------------------------------------------------------------
// Kernel 1 (fused boundary + pass A along y):
// block = (img, x). Computes 4-neighbor boundary flags for row x (border =
// background), packs them as row bitmasks via __ballot, also stores the label
// mask bits (target is exactly 0/1), then h[img][x][y] = (nearest boundary
// bit in this ROW)^2 as u16 (0xFFFF = row empty = exactly BIG).
// All global accesses coalesced. DT symmetry: y-first then x-second pass gives
// the identical exact integer min as the reference's x-then-y order.
// ---------------------------------------------------------------------------
__global__ void k_bnd_passA(const float* __restrict__ inp,
                            const float* __restrict__ tgt,
                            unsigned long long* __restrict__ rows_ib,
                            unsigned long long* __restrict__ rows_lb,
                            unsigned long long* __restrict__ rows_ml,
                            unsigned short* __restrict__ h_ib,
                            unsigned short* __restrict__ h_lb) {
    __shared__ unsigned long long cm1[4];
    __shared__ unsigned long long cm2[4];
    const int img = blockIdx.x >> 8;
    const int x   = blockIdx.x & 255;
    const int y   = threadIdx.x;
    const float* ip = inp + (size_t)img * 65536;
    const float* tp = tgt + (size_t)img * 65536;
    const int idx = x * 256 + y;

    // predicted mask: sigmoid(v) > 0.5  <=>  v > 0
    bool mc = ip[idx] > 0.0f;
    bool mu = (x > 0)   ? (ip[idx - 256] > 0.0f) : false;
    bool md = (x < 255) ? (ip[idx + 256] > 0.0f) : false;
    bool ml = (y > 0)   ? (ip[idx - 1]   > 0.0f) : false;
    bool mr = (y < 255) ? (ip[idx + 1]   > 0.0f) : false;
    bool fib = mc && !(mu && md && ml && mr);

    bool tc = tp[idx] > 0.5f;
    bool tu = (x > 0)   ? (tp[idx - 256] > 0.5f) : false;
    bool td = (x < 255) ? (tp[idx + 256] > 0.5f) : false;
    bool tl = (y > 0)   ? (tp[idx - 1]   > 0.5f) : false;
    bool tr = (y < 255) ? (tp[idx + 1]   > 0.5f) : false;
    bool flb = tc && !(tu && td && tl && tr);

    unsigned long long b1 = __ballot(fib);   // bits over y within this wave
    unsigned long long b2 = __ballot(flb);
    unsigned long long bm = __ballot(tc);    // label mask bits (t == 1)
    if ((y & 63) == 0) {
        const int w = y >> 6;
        const size_t ro = (size_t)blockIdx.x * 4 + w;   // [img][x][w]
        rows_ib[ro] = b1;
        rows_lb[ro] = b2;
        rows_ml[ro] = bm;
        cm1[w] = b1;
        cm2[w] = b2;
    }
    __syncthreads();

    int d1 = nearest_dist2(cm1, y);
    int d2 = nearest_dist2(cm2, y);
    const size_t o = (size_t)blockIdx.x * 256 + y;      // [img][x][y]
    h_ib[o] = (d1 < 0) ? (unsigned short)65535 : (unsigned short)d1;
    h_lb[o] = (d2 < 0) ? (unsigned short)65535 : (unsigned short)d2;
}

// ---------------------------------------------------------------------------
// Kernel 2 (pass B along x + fused loss): block = (img, y), thread = x.
//   d2(x,y) = min_{x'} h[x'][y] + (x-x')^2   via exact early-exit outward scan.
// Lanes that don't consume a distance (m1 only used where flb, m2 where fib)
// init it to 0 so they don't prolong the scan. Then weight map + focal BCE,
// deterministic block reduction -> partials.
// ---------------------------------------------------------------------------
__global__ void k_passB_loss(const unsigned short* __restrict__ h_ib,
                             const unsigned short* __restrict__ h_lb,
                             const unsigned long long* __restrict__ rows_ib,
                             const unsigned long long* __restrict__ rows_lb,
                             const unsigned long long* __restrict__ rows_ml,
                             const float* __restrict__ inp,
                             float* __restrict__ partials) {
    __shared__ float g1[256];
    __shared__ float g2[256];
    __shared__ float wsum[4];
    const int img = blockIdx.x >> 8;
    const int y   = blockIdx.x & 255;
    const int x   = threadIdx.x;

    // column y of h (layout [img][x'][y]); thread x loads x'=x  (L2 scatter)
    {
        const size_t o = ((size_t)img * 256 + x) * 256 + y;
        unsigned short u1 = h_ib[o];
        unsigned short u2 = h_lb[o];
        g1[x] = (u1 == 65535) ? HW_BIG : (float)u1;
        g2[x] = (u2 == 65535) ? HW_BIG : (float)u2;
    }
    const size_t rbase = (size_t)img * 1024 + (size_t)x * 4 + (y >> 6);
    const unsigned long long wib = rows_ib[rbase];
    const unsigned long long wlb = rows_lb[rbase];
    const unsigned long long wml = rows_ml[rbase];
    const int yb = y & 63;
    const bool fib = (wib >> yb) & 1;
    const bool flb = (wlb >> yb) & 1;
    const float t   = ((wml >> yb) & 1) ? 1.0f : 0.0f;   // target is exactly 0/1
    const float v = inp[((size_t)img * 256 + x) * 256 + y];
    __syncthreads();

    // exact early-exit outward scan over x' = x -+ d
    float m1 = flb ? g1[x] : 0.0f;   // d2 to image boundary (used only if flb)
    float m2 = fib ? g2[x] : 0.0f;   // d2 to label boundary (used only if fib)
    for (int d = 1; d < 256; ++d) {
        const float fd2 = (float)(d * d);          // exact integer in f32
        if (fd2 >= m1 && fd2 >= m2) break;
        const int xl = x - d;
        if (xl >= 0)  { m1 = fminf(m1, g1[xl] + fd2); m2 = fminf(m2, g2[xl] + fd2); }
        const int xr = x + d;
        if (xr < 256) { m1 = fminf(m1, g1[xr] + fd2); m2 = fminf(m2, g2[xr] + fd2); }
    }

    const float p = 1.0f / (1.0f + expf(-v));
    float w = 1.0f;
    if (flb) w += expf(-sqrtf(m1));   // THETA=1, SIGMA=1
    if (fib) w += expf(-sqrtf(m2));

    // GAMMA = 1
    float loss = w * (-(1.0f - p) * t * logf(p + LOSS_EPS)
                      - p * (1.0f - t) * logf(1.0f - p + LOSS_EPS));

    // deterministic block reduction: wave shfl tree + 4 wave partials
    float s = loss;
#pragma unroll
    for (int off = 32; off > 0; off >>= 1) s += __shfl_down(s, off, 64);
    const int lane = x & 63, wv = x >> 6;
    if (lane == 0) wsum[wv] = s;
    __syncthreads();
    if (x == 0) partials[blockIdx.x] = (wsum[0] + wsum[1]) + (wsum[2] + wsum[3]);
}

// ---------------------------------------------------------------------------
// Kernel 3: reduce partials -> mean (single block, fixed order, double accum)
// ---------------------------------------------------------------------------
__global__ void k_reduce(const float* __restrict__ partials, int n,
                         float* __restrict__ out, double inv_count) {
    __shared__ double sw[4];
    const int tid = threadIdx.x;
    double s = 0.0;
    for (int i = tid; i < n; i += 256) s += (double)partials[i];
#pragma unroll
    for (int off = 32; off > 0; off >>= 1) s += __shfl_down(s, off, 64);
    const int lane = tid & 63, wv = tid >> 6;
    if (lane == 0) sw[wv] = s;
    __syncthreads();
    if (tid == 0) out[0] = (float)(((sw[0] + sw[1]) + (sw[2] + sw[3])) * inv_count);
}

// ---------------------------------------------------------------------------
extern "C" void kernel_launch(void* const* d_in, const int* in_sizes, int n_in,
                              void* d_out, int out_size, void* d_ws, size_t ws_size,
                              hipStream_t stream) {
    const float* inp = (const float*)d_in[0];
    const float* tgt = (const float*)d_in[1];
    float* out = (float*)d_out;

    const int total = in_sizes[0];          // B*256*256
    const int nimg  = total / 65536;        // B = 8
    const int nblk  = nimg * 256;           // 2048

    char* ws = (char*)d_ws;
    unsigned long long* rows_ib = (unsigned long long*)ws;            // nimg*1024 u64
    unsigned long long* rows_lb = rows_ib + (size_t)nimg * 1024;
    unsigned long long* rows_ml = rows_lb + (size_t)nimg * 1024;
    unsigned short*     h_ib    = (unsigned short*)(rows_ml + (size_t)nimg * 1024);
    unsigned short*     h_lb    = h_ib + (size_t)nimg * 65536;
    float*              parts   = (float*)(h_lb + (size_t)nimg * 65536);

    k_bnd_passA <<<nblk, 256, 0, stream>>>(inp, tgt, rows_ib, rows_lb, rows_ml, h_ib, h_lb);
    k_passB_loss<<<nblk, 256, 0, stream>>>(h_ib, h_lb, rows_ib, rows_lb, rows_ml, inp, parts);
    k_reduce    <<<1,    256, 0, stream>>>(parts, nblk, out, 1.0 / (double)total);
}